// Round 9
// baseline (2581.243 us; speedup 1.0000x reference)
//
#include <hip/hip_runtime.h>

#define Nn 100000
#define Ne 100000
#define NNZC 1600000
#define NBLK 256          // blocks for scatter
#define CHUNK 6250        // NNZC / NBLK
#define BSH 8             // bucket = idx >> 8 (256 ids per bucket)
#define NBK 391           // ceil(100000/256)
#define CAPB 5120         // padded bucket capacity (mean 4096 + 16 sigma)
#define GEMM_TOTAL 1563   // ceil(100000/64)
#define NACC 1568         // 8 XCD x 49 bucket-slots x 4 quarters

typedef __attribute__((ext_vector_type(8))) short short8;
typedef __attribute__((ext_vector_type(4))) float floatx4;

__device__ inline unsigned short f2bf(float f) {
    union { float f; unsigned int i; } c; c.f = f;
    unsigned int i = c.i;
    return (unsigned short)((i + 0x7fffu + ((i >> 16) & 1u)) >> 16);  // RNE
}
__device__ inline unsigned int f2bf2(float lo, float hi) {  // packed RNE
    union { float f; unsigned int i; } a, b;
    a.f = lo; b.f = hi;
    const unsigned int x = (a.i + 0x7fffu + ((a.i >> 16) & 1u)) >> 16;
    const unsigned int y = (b.i + 0x7fffu + ((b.i >> 16) & 1u)) & 0xffff0000u;
    return x | y;
}

// LDS for the scatter+gemm kernel
union FusedLds {
    unsigned short wlds[128 * 136];            // 34816 B (gemm W staging)
    struct { int a[NBK]; int b[NBK]; } s;      // 3128 B (scatter counts/cursors)
};

// ---- gemm block body: h[64 rows] = bf16(x @ W), operand-swapped MFMA ----
__device__ inline void gemm_block(int gb, const float* __restrict__ x,
                                  const float* __restrict__ w,
                                  unsigned short* __restrict__ h,
                                  unsigned short* wlds, int tid) {
    const int wave = tid >> 6, lane = tid & 63;
    const int q = lane >> 4, r16 = lane & 15;

    // stage W: w[k*128+n] fp32 -> wlds[n*136+k] bf16
    for (int i = tid; i < 4096; i += 256) {
        const int k = i >> 5;
        const int n0 = (i & 31) << 2;
        const float4 wv = *(const float4*)(w + k * 128 + n0);
        wlds[(n0 + 0) * 136 + k] = f2bf(wv.x);
        wlds[(n0 + 1) * 136 + k] = f2bf(wv.y);
        wlds[(n0 + 2) * 136 + k] = f2bf(wv.z);
        wlds[(n0 + 3) * 136 + k] = f2bf(wv.w);
    }
    __syncthreads();

    const int row0 = gb * 64 + wave * 16;
    const int rrow = min(row0 + r16, Nn - 1);   // clamp: x ends on a page boundary

    floatx4 acc[8];
#pragma unroll
    for (int jb = 0; jb < 8; ++jb) acc[jb] = (floatx4){0.f, 0.f, 0.f, 0.f};

    const float* ap = x + (size_t)rrow * 128 + q * 8;
#pragma unroll
    for (int kk = 0; kk < 4; ++kk) {
        const float4 a0 = *(const float4*)(ap + kk * 32);
        const float4 a1 = *(const float4*)(ap + kk * 32 + 4);
        union { unsigned int u[4]; short8 s; } xf;
        xf.u[0] = f2bf2(a0.x, a0.y);
        xf.u[1] = f2bf2(a0.z, a0.w);
        xf.u[2] = f2bf2(a1.x, a1.y);
        xf.u[3] = f2bf2(a1.z, a1.w);
        const unsigned short* wp = wlds + kk * 32 + q * 8;
#pragma unroll
        for (int jb = 0; jb < 8; ++jb) {
            const short8 wf = *(const short8*)(wp + (jb * 16 + r16) * 136);
            acc[jb] = __builtin_amdgcn_mfma_f32_16x16x32_bf16(wf, xf.s, acc[jb], 0, 0, 0);
        }
    }

    if (row0 + r16 < Nn) {
        unsigned short* hb = h + (size_t)(row0 + r16) * 128 + q * 4;
#pragma unroll
        for (int jb = 0; jb < 8; ++jb) {
            uint2 o;
            o.x = f2bf2(acc[jb][0], acc[jb][1]);
            o.y = f2bf2(acc[jb][2], acc[jb][3]);
            *(uint2*)(hb + jb * 16) = o;
        }
    }
}

// ---- fused: padded-bucket scatter (blocks [0,NBLK)) + ALL gemm [0, GEMM_TOTAL) ----
// (All GEMM here: acc kernels read h, so GEMM must fully precede them.)
__global__ __launch_bounds__(256) void scatter_gemm_kernel(
        const int* __restrict__ nidx, const int* __restrict__ eidx,
        int* __restrict__ gcurN, int* __restrict__ gcurE,
        unsigned int* __restrict__ pairsN, unsigned int* __restrict__ pairsE,
        const float* __restrict__ x, const float* __restrict__ w,
        unsigned short* __restrict__ h) {
    __shared__ FusedLds sm;
    const int tid = threadIdx.x;
    if (blockIdx.x < NBLK) {
        // pass 1: count
        for (int j = tid; j < NBK; j += 256) { sm.s.a[j] = 0; sm.s.b[j] = 0; }
        __syncthreads();
        const int base = blockIdx.x * CHUNK;
        for (int i = base + tid; i < base + CHUNK; i += 256) {
            atomicAdd(&sm.s.a[nidx[i] >> BSH], 1);
            atomicAdd(&sm.s.b[eidx[i] >> BSH], 1);
        }
        __syncthreads();
        // reserve: LDS slot becomes the block's bucket-local write cursor
        for (int j = tid; j < NBK; j += 256) {
            sm.s.a[j] = atomicAdd(&gcurN[j], sm.s.a[j]);
            sm.s.b[j] = atomicAdd(&gcurE[j], sm.s.b[j]);
        }
        __syncthreads();
        // pass 2: place (idx re-read is L2-hot)
        for (int i = base + tid; i < base + CHUNK; i += 256) {
            const int n = nidx[i], e = eidx[i];
            const int pn = atomicAdd(&sm.s.a[n >> BSH], 1);
            if (pn < CAPB)
                pairsN[(size_t)(n >> BSH) * CAPB + pn] =
                    ((unsigned int)e << 8) | (unsigned int)(n & 255);
            const int pe = atomicAdd(&sm.s.b[e >> BSH], 1);
            if (pe < CAPB)
                pairsE[(size_t)(e >> BSH) * CAPB + pe] =
                    ((unsigned int)n << 8) | (unsigned int)(e & 255);
        }
    } else {
        gemm_block(blockIdx.x - NBLK, x, w, h, sm.wlds, tid);
    }
}

// ---- unordered segment-mean via LDS f32 accumulation (replaces fine+gather) ----
// Block owns 64 ids (quarter of a bucket): scans the bucket's pairs, accumulates
// src rows into acc[64][128] f32 with ds_add_f32, counts degree in-pass, then
// writes mean (MODE 0: bf16 ef row; MODE 1: f32 out row + bias).
// Mapping: j = XCD-coherent so the 4 quarter-blocks of one bucket share an L2:
//   x=j&7, r=j>>3, q=r&3, b = x + 8*(r>>2).
template <int MODE>
__global__ __launch_bounds__(256) void acc_kernel(
        const unsigned int* __restrict__ pairs, const int* __restrict__ gcur,
        const void* __restrict__ srcv, const float* __restrict__ bias,
        void* __restrict__ outv) {
    __shared__ float acc[64][128];              // 32 KB
    __shared__ int cnt[64];
    const int j = blockIdx.x;
    const int xcd = j & 7, r = j >> 3;
    const int q = r & 3;
    const int b = xcd + ((r >> 2) << 3);
    if (b >= NBK) return;
    const int tid = threadIdx.x;
    const int wave = tid >> 6, lane = tid & 63;
    const unsigned int l4 = (unsigned int)lane << 2;

    for (int i = tid; i < 64 * 128; i += 256) (&acc[0][0])[i] = 0.f;
    if (tid < 64) cnt[tid] = 0;
    __syncthreads();

    const int fill = min(gcur[b], CAPB);
    const unsigned int* pb = pairs + (size_t)b * CAPB;
    const char* src = (const char*)srcv;

    for (int i0 = wave << 6; i0 < fill; i0 += 256) {
        const int idx = i0 + lane;
        unsigned int p = 0u;
        bool match = false;
        if (idx < fill) {
            p = pb[idx];
            match = (((p >> 6) & 3u) == (unsigned int)q);
        }
        unsigned long long mask = __ballot(match);
        while (mask) {
            const int l0 = __ffsll((unsigned long long)mask) - 1;
            mask &= mask - 1;
            int l1 = -1;
            if (mask) { l1 = __ffsll((unsigned long long)mask) - 1; mask &= mask - 1; }
            // pair 0: issue load
            const unsigned int p0 = __shfl(p, l0, 64);
            const unsigned int c0 = p0 & 63u;
            const unsigned int u0 = *(const unsigned int*)(src + (((size_t)(p0 >> 8)) << 8) + l4);
            // pair 1: issue load before consuming pair 0 (2 rows in flight)
            unsigned int u1 = 0, c1 = 0;
            if (l1 >= 0) {
                const unsigned int p1 = __shfl(p, l1, 64);
                c1 = p1 & 63u;
                u1 = *(const unsigned int*)(src + (((size_t)(p1 >> 8)) << 8) + l4);
            }
            if (lane == 0) atomicAdd(&cnt[c0], 1);
            atomicAdd(&acc[c0][lane * 2],     __uint_as_float(u0 << 16));
            atomicAdd(&acc[c0][lane * 2 + 1], __uint_as_float(u0 & 0xffff0000u));
            if (l1 >= 0) {
                if (lane == 0) atomicAdd(&cnt[c1], 1);
                atomicAdd(&acc[c1][lane * 2],     __uint_as_float(u1 << 16));
                atomicAdd(&acc[c1][lane * 2 + 1], __uint_as_float(u1 & 0xffff0000u));
            }
        }
    }
    __syncthreads();

    // epilogue: wave w writes ids w, w+4, ... (coalesced full rows)
    const int idbase = (b << 8) + (q << 6);
    for (int i = wave; i < 64; i += 4) {
        const int id = idbase + i;
        if (id >= 100000) continue;    // bucket 390 partial tail
        const int deg = cnt[i];
        const float sinv = deg ? 1.f / (float)deg : 0.f;
        const float a0 = acc[i][lane * 2] * sinv;
        const float a1 = acc[i][lane * 2 + 1] * sinv;
        if (MODE == 0) {
            *(unsigned int*)((char*)outv + (((size_t)id) << 8) + l4) = f2bf2(a0, a1);
        } else {
            const float2 bb = ((const float2*)bias)[lane];
            float2 o;
            o.x = a0 + bb.x;
            o.y = a1 + bb.y;
            *(float2*)((char*)outv + (((size_t)id) << 9) + ((size_t)l4 << 1)) = o;
        }
    }
}

extern "C" void kernel_launch(void* const* d_in, const int* in_sizes, int n_in,
                              void* d_out, int out_size, void* d_ws, size_t ws_size,
                              hipStream_t stream) {
    const float* x = (const float*)d_in[0];
    const float* w = (const float*)d_in[1];
    const float* bias = (const float*)d_in[2];
    const int* hei = (const int*)d_in[3];
    const int* nidx = hei;            // row 0: node indices
    const int* eidx = hei + NNZC;     // row 1: edge indices
    float* out = (float*)d_out;

    // ---- carve workspace (256B-aligned chunks), ~67 MB ----
    char* p = (char*)d_ws;
    unsigned short* h = (unsigned short*)p;  p += (size_t)Nn * 128 * 2;      // 25.6 MB
    unsigned short* ef = (unsigned short*)p; p += (size_t)Ne * 128 * 2;      // 25.6 MB
    int* gcurN = (int*)p;                    p += NBK * 4 + 192;             // bucket fills
    int* gcurE = (int*)p;                    p += NBK * 4 + 192;
    unsigned int* pairsN = (unsigned int*)p; p += (size_t)NBK * CAPB * 4;    // 8.0 MB padded
    unsigned int* pairsE = (unsigned int*)p; p += (size_t)NBK * CAPB * 4;    // 8.0 MB padded

    // zero the bucket-fill cursors (contiguous pair of arrays)
    hipMemsetAsync(gcurN, 0, 2 * (NBK * 4 + 192), stream);

    // ---- 3-launch pipeline: scatter+ALLgemm -> accE (h->ef) -> accN (ef->out) ----
    scatter_gemm_kernel<<<NBLK + GEMM_TOTAL, 256, 0, stream>>>(nidx, eidx, gcurN, gcurE,
                                                               pairsN, pairsE, x, w, h);
    acc_kernel<0><<<NACC, 256, 0, stream>>>(pairsE, gcurE, h, nullptr, ef);
    acc_kernel<1><<<NACC, 256, 0, stream>>>(pairsN, gcurN, ef, bias, out);
}

// Round 10
// 317.306 us; speedup vs baseline: 8.1349x; 8.1349x over previous
//
#include <hip/hip_runtime.h>

#define Nn 100000
#define Ne 100000
#define NNZC 1600000
#define NBLK 256          // blocks for scatter
#define CHUNK 6250        // NNZC / NBLK
#define BSH 8             // bucket = idx >> 8 (256 ids per bucket)
#define NBK 391           // ceil(100000/256)
#define CAPB 5120         // padded bucket capacity (mean 4096 + 16 sigma)
#define GEMM_TOTAL 1563   // ceil(100000/64)
#define NSUB 8            // sub-blocks per bucket (32 ids each)
#define SUBW 32
#define QCAP 1024         // per-sub perm capacity (mean 512 + ~22 sigma)
#define NSG 3136          // 8 xcd-slots * 49 bucket-groups * 8 subs

typedef __attribute__((ext_vector_type(8))) short short8;
typedef __attribute__((ext_vector_type(4))) float floatx4;

__device__ inline unsigned short f2bf(float f) {
    union { float f; unsigned int i; } c; c.f = f;
    unsigned int i = c.i;
    return (unsigned short)((i + 0x7fffu + ((i >> 16) & 1u)) >> 16);  // RNE
}
__device__ inline unsigned int f2bf2(float lo, float hi) {  // packed RNE
    union { float f; unsigned int i; } a, b;
    a.f = lo; b.f = hi;
    const unsigned int x = (a.i + 0x7fffu + ((a.i >> 16) & 1u)) >> 16;
    const unsigned int y = (b.i + 0x7fffu + ((b.i >> 16) & 1u)) & 0xffff0000u;
    return x | y;
}

// LDS for the scatter+gemm kernel
union FusedLds {
    unsigned short wlds[128 * 136];            // 34816 B (gemm W staging)
    struct { int a[NBK]; int b[NBK]; } s;      // 3128 B (scatter counts/cursors)
};

// ---- gemm block body: h[64 rows] = bf16(x @ W), operand-swapped MFMA ----
__device__ inline void gemm_block(int gb, const float* __restrict__ x,
                                  const float* __restrict__ w,
                                  unsigned short* __restrict__ h,
                                  unsigned short* wlds, int tid) {
    const int wave = tid >> 6, lane = tid & 63;
    const int q = lane >> 4, r16 = lane & 15;

    // stage W: w[k*128+n] fp32 -> wlds[n*136+k] bf16
    for (int i = tid; i < 4096; i += 256) {
        const int k = i >> 5;
        const int n0 = (i & 31) << 2;
        const float4 wv = *(const float4*)(w + k * 128 + n0);
        wlds[(n0 + 0) * 136 + k] = f2bf(wv.x);
        wlds[(n0 + 1) * 136 + k] = f2bf(wv.y);
        wlds[(n0 + 2) * 136 + k] = f2bf(wv.z);
        wlds[(n0 + 3) * 136 + k] = f2bf(wv.w);
    }
    __syncthreads();

    const int row0 = gb * 64 + wave * 16;
    const int rrow = min(row0 + r16, Nn - 1);   // clamp: x ends on a page boundary

    floatx4 acc[8];
#pragma unroll
    for (int jb = 0; jb < 8; ++jb) acc[jb] = (floatx4){0.f, 0.f, 0.f, 0.f};

    const float* ap = x + (size_t)rrow * 128 + q * 8;
#pragma unroll
    for (int kk = 0; kk < 4; ++kk) {
        const float4 a0 = *(const float4*)(ap + kk * 32);
        const float4 a1 = *(const float4*)(ap + kk * 32 + 4);
        union { unsigned int u[4]; short8 s; } xf;
        xf.u[0] = f2bf2(a0.x, a0.y);
        xf.u[1] = f2bf2(a0.z, a0.w);
        xf.u[2] = f2bf2(a1.x, a1.y);
        xf.u[3] = f2bf2(a1.z, a1.w);
        const unsigned short* wp = wlds + kk * 32 + q * 8;
#pragma unroll
        for (int jb = 0; jb < 8; ++jb) {
            const short8 wf = *(const short8*)(wp + (jb * 16 + r16) * 136);
            acc[jb] = __builtin_amdgcn_mfma_f32_16x16x32_bf16(wf, xf.s, acc[jb], 0, 0, 0);
        }
    }

    if (row0 + r16 < Nn) {
        unsigned short* hb = h + (size_t)(row0 + r16) * 128 + q * 4;
#pragma unroll
        for (int jb = 0; jb < 8; ++jb) {
            uint2 o;
            o.x = f2bf2(acc[jb][0], acc[jb][1]);
            o.y = f2bf2(acc[jb][2], acc[jb][3]);
            *(uint2*)(hb + jb * 16) = o;
        }
    }
}

// ---- fused: padded-bucket scatter (blocks [0,NBLK)) + ALL gemm [0, GEMM_TOTAL) ----
// (R8-proven. All GEMM here: sortgather kernels read h, so GEMM must precede.)
__global__ __launch_bounds__(256) void scatter_gemm_kernel(
        const int* __restrict__ nidx, const int* __restrict__ eidx,
        int* __restrict__ gcurN, int* __restrict__ gcurE,
        unsigned int* __restrict__ pairsN, unsigned int* __restrict__ pairsE,
        const float* __restrict__ x, const float* __restrict__ w,
        unsigned short* __restrict__ h) {
    __shared__ FusedLds sm;
    const int tid = threadIdx.x;
    if (blockIdx.x < NBLK) {
        // pass 1: count
        for (int j = tid; j < NBK; j += 256) { sm.s.a[j] = 0; sm.s.b[j] = 0; }
        __syncthreads();
        const int base = blockIdx.x * CHUNK;
        for (int i = base + tid; i < base + CHUNK; i += 256) {
            atomicAdd(&sm.s.a[nidx[i] >> BSH], 1);
            atomicAdd(&sm.s.b[eidx[i] >> BSH], 1);
        }
        __syncthreads();
        // reserve: LDS slot becomes the block's bucket-local write cursor
        for (int j = tid; j < NBK; j += 256) {
            sm.s.a[j] = atomicAdd(&gcurN[j], sm.s.a[j]);
            sm.s.b[j] = atomicAdd(&gcurE[j], sm.s.b[j]);
        }
        __syncthreads();
        // pass 2: place (idx re-read is L2-hot)
        for (int i = base + tid; i < base + CHUNK; i += 256) {
            const int n = nidx[i], e = eidx[i];
            const int pn = atomicAdd(&sm.s.a[n >> BSH], 1);
            if (pn < CAPB)
                pairsN[(size_t)(n >> BSH) * CAPB + pn] =
                    ((unsigned int)e << 8) | (unsigned int)(n & 255);
            const int pe = atomicAdd(&sm.s.b[e >> BSH], 1);
            if (pe < CAPB)
                pairsE[(size_t)(e >> BSH) * CAPB + pe] =
                    ((unsigned int)n << 8) | (unsigned int)(e & 255);
        }
    } else {
        gemm_block(blockIdx.x - NBLK, x, w, h, sm.wlds, tid);
    }
}

// ---- fused sort+gather: block owns 32 ids (1/8 bucket) ----
// Counting-sorts its slice of the bucket's pairs into LDS (perm_lds/offs_lds),
// then runs the PROVEN flattened streaming gather (8 loads in flight) with
// offs/perm reads retargeted to LDS. Replaces the separate fine pass entirely.
// blockIdx swizzle pins all 8 subs of a bucket to one XCD (pairs stay L2-local):
//   q = blockIdx; x=q&7; r=q>>3; bg=r%49; sub=r/49; b = x + 8*bg.
template <int MODE>
__global__ __launch_bounds__(256) void sortgather_kernel(
        const unsigned int* __restrict__ pairs, const int* __restrict__ gcur,
        const void* __restrict__ srcv, const float* __restrict__ bias,
        void* __restrict__ outv) {
    __shared__ int perm_lds[QCAP];
    __shared__ int offs_lds[SUBW + 1];
    __shared__ int cnt[SUBW];
    __shared__ int cur[SUBW];
    const int q0 = blockIdx.x;
    const int xs = q0 & 7, r = q0 >> 3;
    const int sub = r / 49;
    const int b = xs + ((r % 49) << 3);
    if (b >= NBK) return;
    const int tid = threadIdx.x;
    const int wave = tid >> 6, lane = tid & 63;

    if (tid < SUBW) cnt[tid] = 0;
    __syncthreads();

    const int fill = min(gcur[b], CAPB);
    const unsigned int* pb = pairs + (size_t)b * CAPB;

    // pass 1: count this sub's local ids (bits 5-7 of p select the sub)
    for (int i = tid; i < fill; i += 256) {
        const unsigned int p = pb[i];
        if (((p >> 5) & 7u) == (unsigned int)sub)
            atomicAdd(&cnt[p & 31u], 1);
    }
    __syncthreads();
    if (tid == 0) {      // 32-entry serial exclusive scan (capped for safety)
        int s = 0;
        for (int i = 0; i < SUBW; ++i) {
            offs_lds[i] = s;
            cur[i] = s;
            s = min(s + cnt[i], QCAP);
        }
        offs_lds[SUBW] = s;
    }
    __syncthreads();
    // pass 2: place (pairs re-read is L2-hot; same XCD via swizzle)
    for (int i = tid; i < fill; i += 256) {
        const unsigned int p = pb[i];
        if (((p >> 5) & 7u) == (unsigned int)sub) {
            const int pos = atomicAdd(&cur[p & 31u], 1);
            if (pos < QCAP) perm_lds[pos] = (int)(p >> 8);
        }
    }
    __syncthreads();

    // ---- proven flattened streaming gather, LDS-fed (wave owns 8 ids) ----
    const int i0 = wave << 3;
    const int start = offs_lds[i0];
    const int end = offs_lds[i0 + 8];
    const int pmax = offs_lds[SUBW] - 1;
    const unsigned int l4 = (unsigned int)lane << 2;
    const char* src = (const char*)srcv;

    float bx = 0.f, by = 0.f;
    if (MODE == 1) {
        const float2 bb = ((const float2*)bias)[lane];
        bx = bb.x; by = bb.y;
    }

    float ax = 0.f, ay = 0.f;
    int e = i0;
    int seg_start = start;
    int nb = offs_lds[i0 + 1];
    const int gidbase = (b << 8) + (sub << 5);

    auto flush = [&](int deg) {
        const int gid = gidbase + e;
        if (gid < 100000) {
            const float sinv = deg ? 1.f / (float)deg : 0.f;
            if (MODE == 0) {
                *(unsigned int*)((char*)outv + (((size_t)gid) << 8) + l4) =
                    f2bf2(ax * sinv, ay * sinv);
            } else {
                float2 o;
                o.x = ax * sinv + bx;
                o.y = ay * sinv + by;
                *(float2*)((char*)outv + (((size_t)gid) << 9) + ((size_t)l4 << 1)) = o;
            }
        }
        ax = 0.f; ay = 0.f;
        ++e;
    };

    int myv = 0;
    for (int i = start; i < end; i += 8) {
        const int t = (i - start) & 63;
        if (t == 0) myv = perm_lds[min(i + lane, pmax)];   // LDS window, no vmcnt
        const int m = min(end - i, 8);
        unsigned int a[8], u[8];
#pragma unroll
        for (int j = 0; j < 8; ++j)
            a[j] = ((unsigned int)__shfl(myv, t + (j < m ? j : m - 1), 64) << 8) | l4;
#pragma unroll
        for (int j = 0; j < 8; ++j) u[j] = *(const unsigned int*)(src + a[j]);
#pragma unroll
        for (int j = 0; j < 8; ++j) {
            if (j < m) {  // wave-uniform
                while (i + j == nb) {  // segment boundary (handles empty segments)
                    flush(nb - seg_start);
                    seg_start = nb;
                    nb = offs_lds[e + 1];
                }
                ax += __uint_as_float(u[j] << 16);
                ay += __uint_as_float(u[j] & 0xffff0000u);
            }
        }
    }
    while (e < i0 + 8) {    // trailing (possibly empty) segments
        flush(end - seg_start);
        seg_start = end;
    }
}

extern "C" void kernel_launch(void* const* d_in, const int* in_sizes, int n_in,
                              void* d_out, int out_size, void* d_ws, size_t ws_size,
                              hipStream_t stream) {
    const float* x = (const float*)d_in[0];
    const float* w = (const float*)d_in[1];
    const float* bias = (const float*)d_in[2];
    const int* hei = (const int*)d_in[3];
    const int* nidx = hei;            // row 0: node indices
    const int* eidx = hei + NNZC;     // row 1: edge indices
    float* out = (float*)d_out;

    // ---- carve workspace (256B-aligned chunks), ~67 MB ----
    char* p = (char*)d_ws;
    unsigned short* h = (unsigned short*)p;  p += (size_t)Nn * 128 * 2;      // 25.6 MB
    unsigned short* ef = (unsigned short*)p; p += (size_t)Ne * 128 * 2;      // 25.6 MB
    int* gcurN = (int*)p;                    p += NBK * 4 + 192;             // bucket fills
    int* gcurE = (int*)p;                    p += NBK * 4 + 192;
    unsigned int* pairsN = (unsigned int*)p; p += (size_t)NBK * CAPB * 4;    // 8.0 MB padded
    unsigned int* pairsE = (unsigned int*)p; p += (size_t)NBK * CAPB * 4;    // 8.0 MB padded

    // zero the bucket-fill cursors (contiguous pair of arrays)
    hipMemsetAsync(gcurN, 0, 2 * (NBK * 4 + 192), stream);

    // ---- 3-launch pipeline: scatter+ALLgemm -> sortgatherE -> sortgatherN ----
    scatter_gemm_kernel<<<NBLK + GEMM_TOTAL, 256, 0, stream>>>(nidx, eidx, gcurN, gcurE,
                                                               pairsN, pairsE, x, w, h);
    sortgather_kernel<0><<<NSG, 256, 0, stream>>>(pairsE, gcurE, h, nullptr, ef);
    sortgather_kernel<1><<<NSG, 256, 0, stream>>>(pairsN, gcurN, ef, bias, out);
}

// Round 11
// 297.132 us; speedup vs baseline: 8.6872x; 1.0679x over previous
//
#include <hip/hip_runtime.h>

#define Nn 100000
#define Ne 100000
#define NNZC 1600000
#define NBLK 256          // blocks for scatter
#define CHUNK 6250        // NNZC / NBLK
#define BSH 8             // bucket = idx >> 8 (256 ids per bucket)
#define BUCKW 256
#define NBK 391           // ceil(100000/256)
#define CAPB 5120         // padded bucket capacity (mean 4096 + 16 sigma)
#define GEMM_TOTAL 391    // ceil(100000/256) -- 256-row tiles, W staged ONCE per block
#define FCAP 4608         // fine-pass LDS pair cache (18 KB)
#define SEGW 4            // segments per wave in gather
#define NG0 6250          // gather virtual blocks

typedef __attribute__((ext_vector_type(8))) short short8;
typedef __attribute__((ext_vector_type(4))) float floatx4;

__device__ inline unsigned short f2bf(float f) {
    union { float f; unsigned int i; } c; c.f = f;
    unsigned int i = c.i;
    return (unsigned short)((i + 0x7fffu + ((i >> 16) & 1u)) >> 16);  // RNE
}
__device__ inline unsigned int f2bf2(float lo, float hi) {  // packed RNE
    union { float f; unsigned int i; } a, b;
    a.f = lo; b.f = hi;
    const unsigned int x = (a.i + 0x7fffu + ((a.i >> 16) & 1u)) >> 16;
    const unsigned int y = (b.i + 0x7fffu + ((b.i >> 16) & 1u)) & 0xffff0000u;
    return x | y;
}

struct FineLds {                               // fine pass (21504 B)
    int cnt[BUCKW];
    int tmp[2][BUCKW];
    unsigned int cache[FCAP];
};
union FineGemmLds {                            // gemm + fineE kernel (34816 B)
    unsigned short wlds[128 * 136];
    FineLds f;
};

// ---- gemm block body: h[256 rows] = bf16(x @ W); W staged ONCE, 4 row-groups ----
__device__ inline void gemm_block256(int gb, const float* __restrict__ x,
                                     const float* __restrict__ w,
                                     unsigned short* __restrict__ h,
                                     unsigned short* wlds, int tid) {
    const int wave = tid >> 6, lane = tid & 63;
    const int q = lane >> 4, r16 = lane & 15;

    // stage W: w[k*128+n] fp32 -> wlds[n*136+k] bf16   (once per 256 rows now)
    for (int i = tid; i < 4096; i += 256) {
        const int k = i >> 5;
        const int n0 = (i & 31) << 2;
        const float4 wv = *(const float4*)(w + k * 128 + n0);
        wlds[(n0 + 0) * 136 + k] = f2bf(wv.x);
        wlds[(n0 + 1) * 136 + k] = f2bf(wv.y);
        wlds[(n0 + 2) * 136 + k] = f2bf(wv.z);
        wlds[(n0 + 3) * 136 + k] = f2bf(wv.w);
    }
    __syncthreads();

#pragma unroll 1
    for (int rg = 0; rg < 4; ++rg) {
        const int row0 = gb * 256 + rg * 64 + wave * 16;
        const int rrow = min(row0 + r16, Nn - 1);   // clamp: x ends on a page boundary

        floatx4 acc[8];
#pragma unroll
        for (int jb = 0; jb < 8; ++jb) acc[jb] = (floatx4){0.f, 0.f, 0.f, 0.f};

        const float* ap = x + (size_t)rrow * 128 + q * 8;
#pragma unroll
        for (int kk = 0; kk < 4; ++kk) {
            const float4 a0 = *(const float4*)(ap + kk * 32);
            const float4 a1 = *(const float4*)(ap + kk * 32 + 4);
            union { unsigned int u[4]; short8 s; } xf;
            xf.u[0] = f2bf2(a0.x, a0.y);
            xf.u[1] = f2bf2(a0.z, a0.w);
            xf.u[2] = f2bf2(a1.x, a1.y);
            xf.u[3] = f2bf2(a1.z, a1.w);
            const unsigned short* wp = wlds + kk * 32 + q * 8;
#pragma unroll
            for (int jb = 0; jb < 8; ++jb) {
                const short8 wf = *(const short8*)(wp + (jb * 16 + r16) * 136);
                acc[jb] = __builtin_amdgcn_mfma_f32_16x16x32_bf16(wf, xf.s, acc[jb], 0, 0, 0);
            }
        }

        if (row0 + r16 < Nn) {
            unsigned short* hb = h + (size_t)(row0 + r16) * 128 + q * 4;
#pragma unroll
            for (int jb = 0; jb < 8; ++jb) {
                uint2 o;
                o.x = f2bf2(acc[jb][0], acc[jb][1]);
                o.y = f2bf2(acc[jb][2], acc[jb][3]);
                *(uint2*)(hb + jb * 16) = o;
            }
        }
    }
}

// ---- standalone padded-bucket scatter (R8-proven logic; tiny LDS -> 8 blocks/CU) ----
__global__ __launch_bounds__(256) void scatter_kernel(
        const int* __restrict__ nidx, const int* __restrict__ eidx,
        int* __restrict__ gcurN, int* __restrict__ gcurE,
        unsigned int* __restrict__ pairsN, unsigned int* __restrict__ pairsE) {
    __shared__ struct { int a[NBK]; int b[NBK]; } sm;
    const int tid = threadIdx.x;
    // pass 1: count
    for (int j = tid; j < NBK; j += 256) { sm.a[j] = 0; sm.b[j] = 0; }
    __syncthreads();
    const int base = blockIdx.x * CHUNK;
    for (int i = base + tid; i < base + CHUNK; i += 256) {
        atomicAdd(&sm.a[nidx[i] >> BSH], 1);
        atomicAdd(&sm.b[eidx[i] >> BSH], 1);
    }
    __syncthreads();
    // reserve: LDS slot becomes the block's bucket-local write cursor
    for (int j = tid; j < NBK; j += 256) {
        sm.a[j] = atomicAdd(&gcurN[j], sm.a[j]);
        sm.b[j] = atomicAdd(&gcurE[j], sm.b[j]);
    }
    __syncthreads();
    // pass 2: place (idx re-read is L2-hot)
    for (int i = base + tid; i < base + CHUNK; i += 256) {
        const int n = nidx[i], e = eidx[i];
        const int pn = atomicAdd(&sm.a[n >> BSH], 1);
        if (pn < CAPB)
            pairsN[(size_t)(n >> BSH) * CAPB + pn] =
                ((unsigned int)e << 8) | (unsigned int)(n & 255);
        const int pe = atomicAdd(&sm.b[e >> BSH], 1);
        if (pe < CAPB)
            pairsE[(size_t)(e >> BSH) * CAPB + pe] =
                ((unsigned int)n << 8) | (unsigned int)(e & 255);
    }
}

// ---- fine block: padded bucket -> compacted CSR (offs + perm); R8-proven ----
__device__ inline void fine_block(int b, const unsigned int* __restrict__ pairs,
                                  const int* __restrict__ gcur,
                                  int* __restrict__ offs, int* __restrict__ perm,
                                  FineLds& L, int t) {
    const int cnt_b = min(gcur[b], CAPB);
    // compacted base S = sum_{j<b} fill_j
    int part = 0;
    for (int j = t; j < b; j += 256) part += min(gcur[j], CAPB);
    L.tmp[0][t] = part;
    __syncthreads();
    for (int off = 128; off > 0; off >>= 1) {
        if (t < off) L.tmp[0][t] += L.tmp[0][t + off];
        __syncthreads();
    }
    const int S = L.tmp[0][0];
    __syncthreads();

    const unsigned int* pb = pairs + (size_t)b * CAPB;
    L.cnt[t] = 0;
    __syncthreads();
    for (int i = t; i < cnt_b; i += BUCKW) {
        const unsigned int p = pb[i];
        if (i < FCAP) L.cache[i] = p;
        atomicAdd(&L.cnt[p & 255u], 1);
    }
    __syncthreads();
    int v = L.cnt[t];
    int pin = 0;
    L.tmp[0][t] = v;
    for (int off = 1; off < BUCKW; off <<= 1) {
        __syncthreads();
        int val = L.tmp[pin][t];
        if (t >= off) val += L.tmp[pin][t - off];
        L.tmp[1 - pin][t] = val;
        pin ^= 1;
    }
    __syncthreads();
    const int excl = L.tmp[pin][t] - v;
    const int id = b * BUCKW + t;
    if (id < 100000) offs[id] = S + excl;
    if (b == NBK - 1 && t == 0) offs[100000] = NNZC;
    __syncthreads();
    L.cnt[t] = excl;   // reuse as cursors (bucket-local)
    __syncthreads();
    for (int i = t; i < cnt_b; i += BUCKW) {
        const unsigned int p = (i < FCAP) ? L.cache[i] : pb[i];
        const int pos = S + atomicAdd(&L.cnt[p & 255u], 1);
        perm[pos] = (int)(p >> 8);
    }
}

// ---- gather body: wave owns SEGW consecutive segments, flattened streaming ----
// (R1/R4/R8 form — proven at the fabric-delivery floor, ~63-66 us.)
template <int MODE>
__device__ inline void gather_body(int gblk, const int* __restrict__ perm,
                                   const int* __restrict__ offs,
                                   const void* __restrict__ srcv,
                                   const float* __restrict__ bias,
                                   void* __restrict__ outv, int tid) {
    const int wave = tid >> 6;
    const int lane = tid & 63;
    const int e0 = __builtin_amdgcn_readfirstlane((gblk * 4 + wave) * SEGW);
    const int start = offs[e0];
    const int end = offs[e0 + SEGW];
    const unsigned int laneoff = (unsigned int)lane << 2;
    const char* src = (const char*)srcv;

    float bx = 0.f, by = 0.f;
    if (MODE == 1) {
        const float2 b = ((const float2*)bias)[lane];
        bx = b.x; by = b.y;
    }

    float ax = 0.f, ay = 0.f;
    int e = e0;
    int seg_start = start;
    int nb = offs[e0 + 1];

    auto flush = [&](int deg) {
        const float sinv = deg ? 1.f / (float)deg : 0.f;
        if (MODE == 0) {
            *(unsigned int*)((char*)outv + (((unsigned int)e << 8) | laneoff)) =
                f2bf2(ax * sinv, ay * sinv);
        } else {
            float2 o;
            o.x = ax * sinv + bx;
            o.y = ay * sinv + by;
            *(float2*)((char*)outv + (((unsigned int)e << 9) | (laneoff << 1))) = o;
        }
        ax = 0.f; ay = 0.f;
        ++e;
    };

    int myv = 0;
    for (int i = start; i < end; i += 8) {
        const int t = (i - start) & 63;
        if (t == 0) myv = perm[min(i + lane, NNZC - 1)];
        const int m = min(end - i, 8);
        unsigned int a[8], u[8];
#pragma unroll
        for (int j = 0; j < 8; ++j)
            a[j] = ((unsigned int)__shfl(myv, t + (j < m ? j : m - 1), 64) << 8) | laneoff;
#pragma unroll
        for (int j = 0; j < 8; ++j) u[j] = *(const unsigned int*)(src + a[j]);
#pragma unroll
        for (int j = 0; j < 8; ++j) {
            if (j < m) {  // wave-uniform
                while (i + j == nb) {  // segment boundary (handles empty segments)
                    flush(nb - seg_start);
                    seg_start = nb;
                    nb = offs[e + 1];
                }
                ax += __uint_as_float(u[j] << 16);
                ay += __uint_as_float(u[j] & 0xffff0000u);
            }
        }
    }
    while (e < e0 + SEGW) {
        flush(end - seg_start);
        seg_start = end;
    }
}

// ---- fused: gemm256 (blocks [0,GEMM_TOTAL)) + fineE (rest) ----
// Both depend only on scatter's outputs -> legal in one launch after scatter.
__global__ __launch_bounds__(256) void gemmE_kernel(
        const float* __restrict__ x, const float* __restrict__ w,
        unsigned short* __restrict__ h,
        const unsigned int* __restrict__ pairsE, const int* __restrict__ gcurE,
        int* __restrict__ offsE, int* __restrict__ permE) {
    __shared__ FineGemmLds sm;
    const int tid = threadIdx.x;
    if (blockIdx.x < GEMM_TOTAL) {
        gemm_block256(blockIdx.x, x, w, h, sm.wlds, tid);
    } else {
        fine_block(blockIdx.x - GEMM_TOTAL, pairsE, gcurE, offsE, permE, sm.f, tid);
    }
}

// ---- fused: fineN first (blocks [0,NBK)), then gather<0> (fabric-bound) ----
__global__ __launch_bounds__(256) void g0_fineN_kernel(
        const int* __restrict__ permE, const int* __restrict__ offsE,
        const unsigned short* __restrict__ h, unsigned short* __restrict__ ef,
        const unsigned int* __restrict__ pairsN, const int* __restrict__ gcurN,
        int* __restrict__ offsN, int* __restrict__ permN) {
    __shared__ FineLds sm;
    const int tid = threadIdx.x;
    if (blockIdx.x < NBK) {
        fine_block(blockIdx.x, pairsN, gcurN, offsN, permN, sm, tid);
    } else {
        gather_body<0>(blockIdx.x - NBK, permE, offsE, h, nullptr, ef, tid);
    }
}

// ---- gather<1>: edges -> nodes, final output ----
__global__ __launch_bounds__(256) void gather_e2n_kernel(
        const int* __restrict__ permN, const int* __restrict__ offsN,
        const unsigned short* __restrict__ ef, const float* __restrict__ bias,
        float* __restrict__ out) {
    gather_body<1>(blockIdx.x, permN, offsN, ef, bias, out, threadIdx.x);
}

extern "C" void kernel_launch(void* const* d_in, const int* in_sizes, int n_in,
                              void* d_out, int out_size, void* d_ws, size_t ws_size,
                              hipStream_t stream) {
    const float* x = (const float*)d_in[0];
    const float* w = (const float*)d_in[1];
    const float* bias = (const float*)d_in[2];
    const int* hei = (const int*)d_in[3];
    const int* nidx = hei;            // row 0: node indices
    const int* eidx = hei + NNZC;     // row 1: edge indices
    float* out = (float*)d_out;

    // ---- carve workspace (256B-aligned chunks), ~81 MB ----
    char* p = (char*)d_ws;
    unsigned short* h = (unsigned short*)p;  p += (size_t)Nn * 128 * 2;      // 25.6 MB
    unsigned short* ef = (unsigned short*)p; p += (size_t)Ne * 128 * 2;      // 25.6 MB
    int* gcurN = (int*)p;                    p += NBK * 4 + 192;             // bucket fills
    int* gcurE = (int*)p;                    p += NBK * 4 + 192;
    int* offsN = (int*)p;                    p += 400128;                    // 100001 ints
    int* offsE = (int*)p;                    p += 400128;
    int* permN = (int*)p;                    p += (size_t)NNZC * 4;          // 6.4 MB
    int* permE = (int*)p;                    p += (size_t)NNZC * 4;          // 6.4 MB
    unsigned int* pairsN = (unsigned int*)p; p += (size_t)NBK * CAPB * 4;    // 8.0 MB padded
    unsigned int* pairsE = (unsigned int*)p; p += (size_t)NBK * CAPB * 4;    // 8.0 MB padded

    // zero the bucket-fill cursors (contiguous pair of arrays)
    hipMemsetAsync(gcurN, 0, 2 * (NBK * 4 + 192), stream);

    // ---- 4-launch pipeline: scatter -> gemm256+fineE -> fineN+gather0 -> gather1 ----
    scatter_kernel<<<NBLK, 256, 0, stream>>>(nidx, eidx, gcurN, gcurE, pairsN, pairsE);
    gemmE_kernel<<<GEMM_TOTAL + NBK, 256, 0, stream>>>(x, w, h, pairsE, gcurE,
                                                       offsE, permE);
    g0_fineN_kernel<<<NBK + NG0, 256, 0, stream>>>(permE, offsE, h, ef,
                                                   pairsN, gcurN, offsN, permN);
    gather_e2n_kernel<<<NG0, 256, 0, stream>>>(permN, offsN, ef, bias, out);
}